// Round 6
// baseline (26.358 us; speedup 1.0000x reference)
//
#include <hip/hip_runtime.h>

// RankNetLoss, n=8192.
// sum over ordered pairs i!=j of [0.5*(1-S)*d + log2(1+exp(-d))].
// The 0.5*(1-S)*d term cancels exactly (S symmetric, d antisymmetric) -> labels irrelevant.
// Fold ordered -> unordered pairs:
//   log2(1+e^{-d}) + log2(1+e^{d}) = |d|/ln2 + 2*log2(1 + 2^{-|d|/ln2}).
// Batch the logs: sum_j log2(1+e_j) = log2( prod_j (1+e_j) ), factors in [1,2].
// Single kernel: block partial * 1/(n(n-1)) atomicAdd'd into out[0] (pre-zeroed
// by a 4-byte memset node). 1056 blocks -> all co-resident, no scheduling tail.

static constexpr int TI = 256;      // i-extent per block (= block threads)
static constexpr int TJ = 128;      // j-extent per block
static constexpr int R  = TI / TJ;  // 2

__global__ __launch_bounds__(256, 8) void rn_main(const float* __restrict__ s,
                                                  float* __restrict__ out,
                                                  int n, int gx, float inv_pairs) {
    // Decode linear active-tile id -> (it, jt). Row it has tiles jt in
    // [it*R, gx-1], count = gx - it*R. Uniform -> scalar loop.
    int rem = blockIdx.x;
    int it = 0;
    while (rem >= gx - it * R) { rem -= gx - it * R; ++it; }
    const int jt = it * R + rem;

    const int t = threadIdx.x;
    const int i = it * TI + t;
    const int j0 = jt * TJ;

    __shared__ float sj[TJ];
    if (t < TJ) {
        int j = j0 + t;
        sj[t] = (j < n) ? s[j] : 0.0f;
    }
    __syncthreads();

    constexpr float INV_LN2 = 1.44269504088896340736f;
    const float si = (i < n) ? s[i] : 0.0f;

    float accD0 = 0.0f, accD1 = 0.0f;  // sum |d|, two chains for ILP
    float prod0 = 1.0f, prod1 = 1.0f;  // prod (1 + 2^{-|d|/ln2}), <= 2^64 each

    const bool clean = (jt >= (it + 1) * R) && (j0 + TJ <= n) && (it * TI + TI <= n);
    if (clean) {
        #pragma unroll 8
        for (int jj = 0; jj < TJ; jj += 2) {
            float d0 = si - sj[jj];
            float d1 = si - sj[jj + 1];
            float e0 = __builtin_amdgcn_exp2f(-fabsf(d0) * INV_LN2);
            float e1 = __builtin_amdgcn_exp2f(-fabsf(d1) * INV_LN2);
            prod0 = __builtin_fmaf(prod0, e0, prod0);   // *= (1+e0)
            prod1 = __builtin_fmaf(prod1, e1, prod1);
            accD0 += fabsf(d0);
            accD1 += fabsf(d1);
        }
    } else {
        #pragma unroll 8
        for (int jj = 0; jj < TJ; ++jj) {
            int j = j0 + jj;
            float d = si - sj[jj];
            float e = __builtin_amdgcn_exp2f(-fabsf(d) * INV_LN2);
            bool ok = (j > i) && (j < n) && (i < n);
            e = ok ? e : 0.0f;                          // masked factor = 1
            prod0 = __builtin_fmaf(prod0, e, prod0);
            accD0 += ok ? fabsf(d) : 0.0f;
        }
    }
    float total = __builtin_fmaf(2.0f,
                                 __builtin_amdgcn_logf(prod0) + __builtin_amdgcn_logf(prod1),
                                 (accD0 + accD1) * INV_LN2);

    // wave reduce (64 lanes)
    for (int off = 32; off > 0; off >>= 1)
        total += __shfl_down(total, off, 64);

    __shared__ float wpart[TI / 64];
    if ((t & 63) == 0) wpart[t >> 6] = total;
    __syncthreads();
    if (t == 0) {
        float b = 0.0f;
        #pragma unroll
        for (int k = 0; k < TI / 64; ++k) b += wpart[k];
        atomicAdd(out, b * inv_pairs);   // one device-scope atomic per block
    }
}

extern "C" void kernel_launch(void* const* d_in, const int* in_sizes, int n_in,
                              void* d_out, int out_size, void* d_ws, size_t ws_size,
                              hipStream_t stream) {
    const float* s = (const float*)d_in[0];
    // d_in[1] (labels) is mathematically irrelevant (antisymmetric term cancels).
    const int n = in_sizes[0];
    float* out = (float*)d_out;

    const int gx = (n + TJ - 1) / TJ;   // j-tiles (64 at n=8192)
    const int gy = (n + TI - 1) / TI;   // i-tiles (32)

    int nactive = 0;
    for (int it = 0; it < gy; ++it) {
        int c = gx - it * R;
        if (c > 0) nactive += c;
    }

    // zero the scalar output (memset node in the captured graph)
    hipMemsetAsync(out, 0, sizeof(float), stream);

    const double npairs = (double)n * (double)(n - 1);
    rn_main<<<nactive, TI, 0, stream>>>(s, out, n, gx, (float)(1.0 / npairs));
}

// Round 7
// 17.101 us; speedup vs baseline: 1.5413x; 1.5413x over previous
//
#include <hip/hip_runtime.h>

// RankNetLoss, n=8192.
// sum over ordered pairs i!=j of [0.5*(1-S)*d + log2(1+exp(-d))].
// The 0.5*(1-S)*d term cancels exactly (S symmetric, d antisymmetric) -> labels irrelevant.
// Fold ordered -> unordered pairs:
//   log2(1+e^{-d}) + log2(1+e^{d}) = |d|/ln2 + 2*log2(1 + 2^{-|d|/ln2}).
// Batch the logs: sum_j log2(1+e_j) = log2( prod_j (1+e_j) ), factors in [1,2].
// Two chains per thread -> ILP and prod <= 2^64 (fp32-safe).
// Two kernels, dense part[] (no atomics — round 6 showed 1056 simultaneous
// same-address atomics serialize for ~10us).

static constexpr int TI = 256;      // i-extent per block (= block threads)
static constexpr int TJ = 128;      // j-extent per block
static constexpr int R  = TI / TJ;  // 2

__global__ __launch_bounds__(256, 8) void rn_main(const float* __restrict__ s,
                                                  float* __restrict__ part,
                                                  int n, int gx) {
    // Decode linear active-tile id -> (it, jt). Row it has tiles jt in
    // [it*R, gx-1], count = gx - it*R. Uniform -> scalar loop.
    int rem = blockIdx.x;
    int it = 0;
    while (rem >= gx - it * R) { rem -= gx - it * R; ++it; }
    const int jt = it * R + rem;

    const int t = threadIdx.x;
    const int i = it * TI + t;
    const int j0 = jt * TJ;

    __shared__ float sj[TJ];
    if (t < TJ) {
        int j = j0 + t;
        sj[t] = (j < n) ? s[j] : 0.0f;
    }
    __syncthreads();

    constexpr float INV_LN2 = 1.44269504088896340736f;
    const float si = (i < n) ? s[i] : 0.0f;

    float accD0 = 0.0f, accD1 = 0.0f;  // sum |d|, two chains for ILP
    float prod0 = 1.0f, prod1 = 1.0f;  // prod (1 + 2^{-|d|/ln2}), <= 2^64 each

    const bool clean = (jt >= (it + 1) * R) && (j0 + TJ <= n) && (it * TI + TI <= n);
    if (clean) {
        #pragma unroll 8
        for (int jj = 0; jj < TJ; jj += 2) {
            float d0 = si - sj[jj];
            float d1 = si - sj[jj + 1];
            float e0 = __builtin_amdgcn_exp2f(-fabsf(d0) * INV_LN2);
            float e1 = __builtin_amdgcn_exp2f(-fabsf(d1) * INV_LN2);
            prod0 = __builtin_fmaf(prod0, e0, prod0);   // *= (1+e0)
            prod1 = __builtin_fmaf(prod1, e1, prod1);
            accD0 += fabsf(d0);
            accD1 += fabsf(d1);
        }
    } else {
        #pragma unroll 8
        for (int jj = 0; jj < TJ; jj += 2) {
            int ja = j0 + jj, jb = j0 + jj + 1;
            float d0 = si - sj[jj];
            float d1 = si - sj[jj + 1];
            float e0 = __builtin_amdgcn_exp2f(-fabsf(d0) * INV_LN2);
            float e1 = __builtin_amdgcn_exp2f(-fabsf(d1) * INV_LN2);
            bool ok0 = (ja > i) && (ja < n) && (i < n);
            bool ok1 = (jb > i) && (jb < n) && (i < n);
            e0 = ok0 ? e0 : 0.0f;                       // masked factor = 1
            e1 = ok1 ? e1 : 0.0f;
            prod0 = __builtin_fmaf(prod0, e0, prod0);
            prod1 = __builtin_fmaf(prod1, e1, prod1);
            accD0 += ok0 ? fabsf(d0) : 0.0f;
            accD1 += ok1 ? fabsf(d1) : 0.0f;
        }
    }
    float total = __builtin_fmaf(2.0f,
                                 __builtin_amdgcn_logf(prod0) + __builtin_amdgcn_logf(prod1),
                                 (accD0 + accD1) * INV_LN2);

    // wave reduce (64 lanes)
    for (int off = 32; off > 0; off >>= 1)
        total += __shfl_down(total, off, 64);

    __shared__ float wpart[TI / 64];
    if ((t & 63) == 0) wpart[t >> 6] = total;
    __syncthreads();
    if (t == 0) {
        float b = 0.0f;
        #pragma unroll
        for (int k = 0; k < TI / 64; ++k) b += wpart[k];
        part[blockIdx.x] = b;   // dense, no atomics, no pre-zero needed
    }
}

__global__ __launch_bounds__(1024) void rn_final(const float* __restrict__ part,
                                                 float* __restrict__ out,
                                                 int nblocks, float inv_pairs) {
    const int t = threadIdx.x;
    float a = 0.0f;
    for (int k = t; k < nblocks; k += 1024) a += part[k];
    for (int off = 32; off > 0; off >>= 1)
        a += __shfl_down(a, off, 64);
    __shared__ float wp[16];
    if ((t & 63) == 0) wp[t >> 6] = a;
    __syncthreads();
    if (t == 0) {
        float b = 0.0f;
        #pragma unroll
        for (int k = 0; k < 16; ++k) b += wp[k];
        out[0] = b * inv_pairs;
    }
}

extern "C" void kernel_launch(void* const* d_in, const int* in_sizes, int n_in,
                              void* d_out, int out_size, void* d_ws, size_t ws_size,
                              hipStream_t stream) {
    const float* s = (const float*)d_in[0];
    // d_in[1] (labels) is mathematically irrelevant (antisymmetric term cancels).
    const int n = in_sizes[0];

    float* part = (float*)d_ws;
    float* out = (float*)d_out;

    const int gx = (n + TJ - 1) / TJ;   // j-tiles (64 at n=8192)
    const int gy = (n + TI - 1) / TI;   // i-tiles (32)

    int nactive = 0;
    for (int it = 0; it < gy; ++it) {
        int c = gx - it * R;
        if (c > 0) nactive += c;
    }
    // n=8192: nactive = 1056 <= 2048 co-resident capacity -> single round.

    rn_main<<<nactive, TI, 0, stream>>>(s, part, n, gx);

    const double npairs = (double)n * (double)(n - 1);
    rn_final<<<1, 1024, 0, stream>>>(part, out, nactive, (float)(1.0 / npairs));
}

// Round 8
// 14.742 us; speedup vs baseline: 1.7880x; 1.1600x over previous
//
#include <hip/hip_runtime.h>

// RankNetLoss, n=8192.
// sum over ordered pairs i!=j of [0.5*(1-S)*d + log2(1+exp(-d))].
// The 0.5*(1-S)*d term cancels exactly (S symmetric, d antisymmetric) -> labels irrelevant.
// Fold ordered -> unordered pairs, work in log2 domain with PRE-SCALED scores
// (s' = s/ln2):  a = |s'_i - s'_j|;  pair cost = a + 2*log2(1+2^{-a}).
// Batch the logs: sum_j log2(1+e_j) = log2( prod_j (1+e_j) ), factors in [1,2],
// <= 32 factors/chain -> prod <= 2^32 (fp32-safe).
// Inner loop per pair: v_sub, v_add(|x|), v_fma, v_exp(-|x|) — 4 instructions.

static constexpr int TI = 256;      // i-extent per block (= block threads)
static constexpr int TJ = 64;       // j-extent per block
static constexpr int R  = TI / TJ;  // 4

__global__ __launch_bounds__(256, 8) void rn_main(const float* __restrict__ s,
                                                  float* __restrict__ part,
                                                  int n, int gx) {
    // Decode linear active-tile id -> (it, jt). Row it has tiles jt in
    // [it*R, gx-1], count = gx - it*R. Uniform -> scalar loop.
    int rem = blockIdx.x;
    int it = 0;
    while (rem >= gx - it * R) { rem -= gx - it * R; ++it; }
    const int jt = it * R + rem;

    const int t = threadIdx.x;
    const int i = it * TI + t;
    const int j0 = jt * TJ;

    constexpr float INV_LN2 = 1.44269504088896340736f;

    __shared__ float sj[TJ];                 // pre-scaled: s[j]/ln2
    if (t < TJ) {
        int j = j0 + t;
        sj[t] = ((j < n) ? s[j] : 0.0f) * INV_LN2;
    }
    __syncthreads();

    const float si = ((i < n) ? s[i] : 0.0f) * INV_LN2;

    float accA = 0.0f;                 // sum a  (= sum |d|/ln2)
    float prod0 = 1.0f, prod1 = 1.0f;  // prod (1 + 2^{-a}), two chains for ILP

    const bool clean = (jt >= (it + 1) * R) && (j0 + TJ <= n) && (it * TI + TI <= n);
    if (clean) {
        #pragma unroll 8
        for (int jj = 0; jj < TJ; jj += 2) {
            float x0 = si - sj[jj];                       // ds_read2 -> broadcast
            float x1 = si - sj[jj + 1];
            float e0 = __builtin_amdgcn_exp2f(-fabsf(x0)); // -abs = free src mod
            float e1 = __builtin_amdgcn_exp2f(-fabsf(x1));
            accA += fabsf(x0);                             // abs = free src mod
            accA += fabsf(x1);
            prod0 = __builtin_fmaf(prod0, e0, prod0);      // *= (1+e0)
            prod1 = __builtin_fmaf(prod1, e1, prod1);
        }
    } else {
        #pragma unroll 8
        for (int jj = 0; jj < TJ; jj += 2) {
            int ja = j0 + jj, jb = j0 + jj + 1;
            float x0 = si - sj[jj];
            float x1 = si - sj[jj + 1];
            float e0 = __builtin_amdgcn_exp2f(-fabsf(x0));
            float e1 = __builtin_amdgcn_exp2f(-fabsf(x1));
            bool ok0 = (ja > i) && (ja < n) && (i < n);
            bool ok1 = (jb > i) && (jb < n) && (i < n);
            accA += ok0 ? fabsf(x0) : 0.0f;
            accA += ok1 ? fabsf(x1) : 0.0f;
            prod0 = __builtin_fmaf(prod0, ok0 ? e0 : 0.0f, prod0);  // masked factor = 1
            prod1 = __builtin_fmaf(prod1, ok1 ? e1 : 0.0f, prod1);
        }
    }
    float total = __builtin_fmaf(2.0f,
                                 __builtin_amdgcn_logf(prod0) + __builtin_amdgcn_logf(prod1),
                                 accA);

    // wave reduce (64 lanes)
    for (int off = 32; off > 0; off >>= 1)
        total += __shfl_down(total, off, 64);

    __shared__ float wpart[TI / 64];
    if ((t & 63) == 0) wpart[t >> 6] = total;
    __syncthreads();
    if (t == 0) {
        float b = 0.0f;
        #pragma unroll
        for (int k = 0; k < TI / 64; ++k) b += wpart[k];
        part[blockIdx.x] = b;   // dense, no atomics, no pre-zero needed
    }
}

__global__ __launch_bounds__(1024) void rn_final(const float* __restrict__ part,
                                                 float* __restrict__ out,
                                                 int nblocks, float inv_pairs) {
    const int t = threadIdx.x;
    float a = 0.0f;
    for (int k = t; k < nblocks; k += 1024) a += part[k];
    for (int off = 32; off > 0; off >>= 1)
        a += __shfl_down(a, off, 64);
    __shared__ float wp[16];
    if ((t & 63) == 0) wp[t >> 6] = a;
    __syncthreads();
    if (t == 0) {
        float b = 0.0f;
        #pragma unroll
        for (int k = 0; k < 16; ++k) b += wp[k];
        out[0] = b * inv_pairs;
    }
}

extern "C" void kernel_launch(void* const* d_in, const int* in_sizes, int n_in,
                              void* d_out, int out_size, void* d_ws, size_t ws_size,
                              hipStream_t stream) {
    const float* s = (const float*)d_in[0];
    // d_in[1] (labels) is mathematically irrelevant (antisymmetric term cancels).
    const int n = in_sizes[0];

    float* part = (float*)d_ws;
    float* out = (float*)d_out;

    const int gx = (n + TJ - 1) / TJ;   // j-tiles (128 at n=8192)
    const int gy = (n + TI - 1) / TI;   // i-tiles (32)

    int nactive = 0;
    for (int it = 0; it < gy; ++it) {
        int c = gx - it * R;
        if (c > 0) nactive += c;
    }

    rn_main<<<nactive, TI, 0, stream>>>(s, part, n, gx);

    const double npairs = (double)n * (double)(n - 1);
    rn_final<<<1, 1024, 0, stream>>>(part, out, nactive, (float)(1.0 / npairs));
}